// Round 5
// baseline (599.905 us; speedup 1.0000x reference)
//
#include <hip/hip_runtime.h>
#include <hip/hip_fp16.h>

// Triplane bilinear sampling, two-phase with DUAL fp16 transposed grids:
//   Phase 1: LDS-tiled transpose+downconvert (32,R,R) fp32 -> (R,R,32) fp16,
//            written TWICE: copy A (natural) and copy B (x-shifted by one:
//            B[y][x] = A[y][x+1], B[y][R-1] = A[y][R-1]). Exact 1D grid,
//            level decoded from blockIdx (no no-op blocks).
//   Phase 2: gather. 2 threads per (point,grid); each owns 16 channels.
//            Copy chosen by parity of x0 so the (x0,x1) pair is ONE fully
//            used 128-B line; 8x 16 B loads, fp32 lerp, 4x 16 B NT stores.
//
// Lessons: Morton sort (locality) = null; fp16 (bytes) = win; dual-copy
//   (line util) = +12us -> reads served at cache-class BW (~25 TB/s), so
//   remaining fat is issue/VALU duplication, not read bytes. This round
//   halves gather waves (16ch/lane) and removes transpose no-op blocks.
//
// Output layout: out[n][c], c = b*32 + ch, b = level*3 + plane. fp32.

typedef float        f32x4 __attribute__((ext_vector_type(4)));
typedef unsigned int u32x4 __attribute__((ext_vector_type(4)));

struct GridPtrs { const float* g[9]; };
struct GridOffs { size_t off[9]; };   // half-element offsets of copy A grids

#define TP_TEX 64                      // texels per transpose tile (one block)
#define TOTAL_HALVES 33030144ull       // 3*(2^19 + 2^21 + 2^23); copy B base

// ---------------- Phase 1: LDS-tiled transpose fp32 -> fp16 (A + B) -------
// Exact grid: 16128 blocks. bid < 768 -> L0 (256 tiles/grid); < 3840 -> L1
// (1024 tiles/grid); else L2 (4096 tiles/grid). Tiles never cross a row.
__global__ __launch_bounds__(256) void transpose_grids_h_kernel(
    GridPtrs gp, GridOffs go, __half* __restrict__ t)
{
    const int bid = blockIdx.x;
    int l, b, tile;
    if (bid < 768)       { l = 0; b = bid >> 8;                 tile = bid & 255; }
    else if (bid < 3840) { l = 1; b = 3 + ((bid - 768) >> 10);  tile = (bid - 768) & 1023; }
    else                 { l = 2; b = 6 + ((bid - 3840) >> 12); tile = (bid - 3840) & 4095; }

    const int R = 128 << l;
    const int T = R * R;
    const int tile0 = tile * TP_TEX;

    __shared__ unsigned short lds[TP_TEX * 33];

    const int tid = threadIdx.x;

    // stage-in: thread t: ch = t>>3, part = (t&7)*8 -> two float4 loads
    // (nontemporal: stream-once), convert, scatter into lds[tex][ch].
    {
        const int ch   = tid >> 3;          // 0..31
        const int part = (tid & 7) << 3;    // 0..56
        const float* __restrict__ src = gp.g[b] + (size_t)ch * (size_t)T + tile0 + part;
        const f32x4 a0 = __builtin_nontemporal_load((const f32x4*)src);
        const f32x4 a1 = __builtin_nontemporal_load((const f32x4*)(src + 4));
#pragma unroll
        for (int k = 0; k < 4; ++k)
            lds[(part + k) * 33 + ch] = __half_as_ushort(__float2half_rn(a0[k]));
#pragma unroll
        for (int k = 0; k < 4; ++k)
            lds[(part + 4 + k) * 33 + ch] = __half_as_ushort(__float2half_rn(a1[k]));
    }
    __syncthreads();

    // stage-out: thread t: tex = t>>2, q = (t&3)*8 -> pack 8 halves, write
    // copy A at texel g, copy B at g-1 (x>=1), edge duplicate B[g] at x==R-1.
    {
        const int tex = tid >> 2;           // 0..63
        const int q   = (tid & 3) << 3;     // 0,8,16,24
        const unsigned short* row = &lds[tex * 33 + q];
        u32x4 v;
#pragma unroll
        for (int k = 0; k < 4; ++k) {
            const unsigned lo = row[2 * k];
            const unsigned hi = row[2 * k + 1];
            v[k] = lo | (hi << 16);
        }
        const int g = tile0 + tex;
        const int x = g & (R - 1);          // R is a power of two

        __half* A = t + go.off[b];
        __half* B = t + TOTAL_HALVES + go.off[b];

        *(u32x4*)(A + (size_t)g * 32 + q) = v;
        if (x >= 1)     *(u32x4*)(B + (size_t)(g - 1) * 32 + q) = v;
        if (x == R - 1) *(u32x4*)(B + (size_t)g       * 32 + q) = v;
    }
}

// ---------------- Phase 2: gather (dual fp16 transposed grids) ------------
__device__ __forceinline__ void h8_to_f(const uint4 u, float f[8])
{
    const __half2* h = (const __half2*)&u;
#pragma unroll
    for (int i = 0; i < 4; ++i) {
        const float2 t = __half22float2(h[i]);
        f[2 * i + 0] = t.x;
        f[2 * i + 1] = t.y;
    }
}

__global__ __launch_bounds__(256) void triplane_sample_h_kernel(
    const float* __restrict__ pts,
    const __half* __restrict__ tg,
    float* __restrict__ out,
    int n_pts)
{
    const int tid = blockIdx.x * 256 + threadIdx.x;
    const int total = n_pts * 18;           // 9 grids * 2 channel-halves
    if (tid >= total) return;

    const int n  = tid / 18;
    const int r  = tid - n * 18;            // 0..17
    const int b  = r >> 1;                  // grid index 0..8
    const int q  = (r & 1) << 4;            // channel start: 0 or 16
    const int l  = (b >= 6) ? 2 : (b >= 3 ? 1 : 0);
    const int p  = b - l * 3;               // plane 0,1,2

    const float vx = pts[n * 3 + 0];
    const float vy = pts[n * 3 + 1];
    const float vz = pts[n * 3 + 2];

    // Exactly the reference arithmetic: (v - BOUNDS) * (2/(-2*BOUNDS)) - 1
    const float scale = 2.0f / (-2.0f * 1.6f);   // -0.625
    const float px = (vx - 1.6f) * scale - 1.0f;
    const float py = (vy - 1.6f) * scale - 1.0f;
    const float pz = (vz - 1.6f) * scale - 1.0f;

    // plane 0: (y,z)  plane 1: (x,z)  plane 2: (x,y)
    const float cx = (p == 0) ? py : px;
    const float cy = (p == 2) ? py : pz;

    const int   R   = 128 << l;
    const float Rm1 = (float)(R - 1);

    float x = (cx + 1.0f) * 0.5f * Rm1;
    float y = (cy + 1.0f) * 0.5f * Rm1;
    x = fminf(fmaxf(x, 0.0f), Rm1);
    y = fminf(fmaxf(y, 0.0f), Rm1);

    const float x0f = floorf(x);
    const float y0f = floorf(y);
    const float wx  = x - x0f;
    const float wy  = y - y0f;
    const int x0 = (int)x0f;
    const int y0 = (int)y0f;
    const int y1 = min(y0 + 1, R - 1);

    // Parity-aligned pair read: copy A when x0 even, x-shifted copy B when
    // x0 odd. Either way v00 = block xb, v01 = block xb+1 (same 128-B line),
    // with the x1 = min(x0+1, R-1) clamp baked into copy B's edge column.
    const int par = x0 & 1;
    const int xb  = x0 - par;               // even

    // off(b) = base(l) + p * (524288 << 2l)   [half elements]
    const size_t lbase = (l == 0) ? 0ull : ((l == 1) ? 1572864ull : 7864320ull);
    const size_t off_b = lbase + ((size_t)p << (19 + 2 * l));

    const __half* gbase = tg + (par ? TOTAL_HALVES : 0ull) + off_b + q;
    const size_t r0 = ((size_t)(y0 * R + xb)) * 32;
    const size_t r1 = ((size_t)(y1 * R + xb)) * 32;

    // 8x 16 B loads, issued together for MLP: channels q..q+7 (batch a) and
    // q+8..q+15 (batch b) of the 4 corners.
    const uint4 u00a = *(const uint4*)(gbase + r0);
    const uint4 u00b = *(const uint4*)(gbase + r0 + 8);
    const uint4 u01a = *(const uint4*)(gbase + r0 + 32);
    const uint4 u01b = *(const uint4*)(gbase + r0 + 40);
    const uint4 u10a = *(const uint4*)(gbase + r1);
    const uint4 u10b = *(const uint4*)(gbase + r1 + 8);
    const uint4 u11a = *(const uint4*)(gbase + r1 + 32);
    const uint4 u11b = *(const uint4*)(gbase + r1 + 40);

    const float omwx = 1.0f - wx;
    const float omwy = 1.0f - wy;

    float resa[8], resb[8];
    {
        float f00[8], f01[8], f10[8], f11[8];
        h8_to_f(u00a, f00); h8_to_f(u01a, f01);
        h8_to_f(u10a, f10); h8_to_f(u11a, f11);
#pragma unroll
        for (int k = 0; k < 8; ++k)
            resa[k] = (f00[k] * omwx + f01[k] * wx) * omwy
                    + (f10[k] * omwx + f11[k] * wx) * wy;
    }
    {
        float f00[8], f01[8], f10[8], f11[8];
        h8_to_f(u00b, f00); h8_to_f(u01b, f01);
        h8_to_f(u10b, f10); h8_to_f(u11b, f11);
#pragma unroll
        for (int k = 0; k < 8; ++k)
            resb[k] = (f00[k] * omwx + f01[k] * wx) * omwy
                    + (f10[k] * omwx + f11[k] * wx) * wy;
    }

    // Nontemporal: the 346 MB output stream must not evict the grids from L3.
    float* op = out + (size_t)n * 288 + b * 32 + q;
    const f32x4 r0v = {resa[0], resa[1], resa[2], resa[3]};
    const f32x4 r1v = {resa[4], resa[5], resa[6], resa[7]};
    const f32x4 r2v = {resb[0], resb[1], resb[2], resb[3]};
    const f32x4 r3v = {resb[4], resb[5], resb[6], resb[7]};
    __builtin_nontemporal_store(r0v, (f32x4*)op);
    __builtin_nontemporal_store(r1v, (f32x4*)(op + 4));
    __builtin_nontemporal_store(r2v, (f32x4*)(op + 8));
    __builtin_nontemporal_store(r3v, (f32x4*)(op + 12));
}

// ---------------- Fallback: direct gather on channel-major fp32 grids -----
__global__ __launch_bounds__(256) void triplane_sample_kernel(
    const float* __restrict__ pts,
    GridPtrs gp,
    float* __restrict__ out,
    int n_pts)
{
    const int tid = blockIdx.x * 256 + threadIdx.x;
    const int total = n_pts * 72;
    if (tid >= total) return;

    const int n  = tid / 72;
    const int c4 = tid - n * 72;
    const int b  = c4 >> 3;
    const int ch = (c4 & 7) << 2;
    const int l  = (b >= 6) ? 2 : (b >= 3 ? 1 : 0);
    const int p  = b - l * 3;

    const float vx = pts[n * 3 + 0];
    const float vy = pts[n * 3 + 1];
    const float vz = pts[n * 3 + 2];

    const float scale = 2.0f / (-2.0f * 1.6f);
    const float px = (vx - 1.6f) * scale - 1.0f;
    const float py = (vy - 1.6f) * scale - 1.0f;
    const float pz = (vz - 1.6f) * scale - 1.0f;

    const float cx = (p == 0) ? py : px;
    const float cy = (p == 2) ? py : pz;

    const int   R   = 128 << l;
    const float Rm1 = (float)(R - 1);

    float x = (cx + 1.0f) * 0.5f * Rm1;
    float y = (cy + 1.0f) * 0.5f * Rm1;
    x = fminf(fmaxf(x, 0.0f), Rm1);
    y = fminf(fmaxf(y, 0.0f), Rm1);

    const float x0f = floorf(x);
    const float y0f = floorf(y);
    const float wx  = x - x0f;
    const float wy  = y - y0f;
    const int x0 = (int)x0f;
    const int y0 = (int)y0f;
    const int x1 = min(x0 + 1, R - 1);
    const int y1 = min(y0 + 1, R - 1);

    const size_t RR   = (size_t)R * (size_t)R;
    const float* base = gp.g[b] + (size_t)ch * RR;

    const int i00 = y0 * R + x0;
    const int i01 = y0 * R + x1;
    const int i10 = y1 * R + x0;
    const int i11 = y1 * R + x1;

    const float omwx = 1.0f - wx;
    const float omwy = 1.0f - wy;

    float rr[4];
#pragma unroll
    for (int k = 0; k < 4; ++k) {
        const float* gk = base + (size_t)k * RR;
        rr[k] = (gk[i00] * omwx + gk[i01] * wx) * omwy
              + (gk[i10] * omwx + gk[i11] * wx) * wy;
    }
    ((float4*)out)[tid] = make_float4(rr[0], rr[1], rr[2], rr[3]);
}

extern "C" void kernel_launch(void* const* d_in, const int* in_sizes, int n_in,
                              void* d_out, int out_size, void* d_ws, size_t ws_size,
                              hipStream_t stream)
{
    const float* pts = (const float*)d_in[0];
    GridPtrs gp;
    for (int i = 0; i < 9; ++i) gp.g[i] = (const float*)d_in[1 + i];
    float* out = (float*)d_out;

    const int n_pts = in_sizes[0] / 3;       // 300000
    const int block = 256;

    // Copy-A half-element offsets; copy B lives at +TOTAL_HALVES.
    GridOffs go;
    size_t off = 0;
    for (int b = 0; b < 9; ++b) {
        go.off[b] = off;
        const int R = 128 << (b / 3);
        off += (size_t)32 * R * R;
    }
    const size_t needed_bytes = 2 * off * sizeof(__half);   // ~132 MB (A + B)

    if (ws_size >= needed_bytes) {
        __half* tg = (__half*)d_ws;
        // Phase 1: LDS-tiled transpose+convert, dual-copy write.
        // Exact grid: 3*(256 + 1024 + 4096) = 16128 tiles.
        transpose_grids_h_kernel<<<16128, block, 0, stream>>>(gp, go, tg);
        // Phase 2: gather. 2 threads/(point,grid), 16 channels each.
        const int total = n_pts * 18;
        const int grid  = (total + block - 1) / block;
        triplane_sample_h_kernel<<<grid, block, 0, stream>>>(pts, tg, out, n_pts);
    } else {
        const int total = n_pts * 72;
        const int grid  = (total + block - 1) / block;
        triplane_sample_kernel<<<grid, block, 0, stream>>>(pts, gp, out, n_pts);
    }
}

// Round 6
// 538.614 us; speedup vs baseline: 1.1138x; 1.1138x over previous
//
#include <hip/hip_runtime.h>
#include <hip/hip_fp16.h>

// Triplane bilinear sampling, two-phase with DUAL fp16 transposed grids:
//   Phase 1: LDS-tiled transpose+downconvert (32,R,R) fp32 -> (R,R,32) fp16,
//            written TWICE: copy A (natural) and copy B (x-shifted by one
//            texel: B[y][x] = A[y][x+1], B[y][R-1] = A[y][R-1]).
//   Phase 2: gather. 4 threads per (point,grid); each owns 8 channels.
//            Copy chosen by parity of x0 so the (x0,x1) 64B-block pair ALWAYS
//            sits in one fully-used 128-B cache line -> 2 fully-used lines
//            per (point,grid) = read line-traffic floor for 32xfp16.
//            fp32 lerp, 2x 16 B nontemporal stores.
//
// Round-5 lesson (lane structure): 2 lanes x 16ch regressed +60us — the 8
// in-flight uint4 + wide float arrays cross the 64-VGPR occupancy cliff
// (8 -> 4 waves/SIMD) and the gather is latency-hiding-sensitive. The 4-lane
// x 8ch shape (4 loads/lane, <=64 VGPR, 8 waves/SIMD) is the optimum; both
// neighbors (8x4, 2x16) measured worse. This file is the verbatim R4 winner
// (539.4 us).
//
// Output layout: out[n][c], c = b*32 + ch, b = level*3 + plane. fp32.

typedef float        f32x4 __attribute__((ext_vector_type(4)));
typedef unsigned int u32x4 __attribute__((ext_vector_type(4)));

struct GridPtrs { const float* g[9]; };
struct GridOffs { size_t off[9]; };   // half-element offsets of copy A grids

#define TP_TEX 64                      // texels per transpose tile (one block)
#define TOTAL_HALVES 33030144ull       // 3*(2^19 + 2^21 + 2^23); copy B base

// ---------------- Phase 1: LDS-tiled transpose fp32 -> fp16 (A + B) -------
// gridDim.y = b (0..8); gridDim.x covers T/64 tiles of the largest grid,
// smaller grids early-out. Tiles are 64 texels and never cross a row
// (R % 64 == 0), so the x-shift logic is per-thread local.
__global__ __launch_bounds__(256) void transpose_grids_h_kernel(
    GridPtrs gp, GridOffs go, __half* __restrict__ t)
{
    const int b = blockIdx.y;
    const int l = b / 3;
    const int R = 128 << l;
    const int T = R * R;

    const int tile0 = blockIdx.x * TP_TEX;
    if (tile0 >= T) return;

    __shared__ unsigned short lds[TP_TEX * 33];

    const int tid = threadIdx.x;

    // stage-in: thread t: ch = t>>3, part = (t&7)*8 -> two float4 loads,
    // convert, scatter into lds[tex][ch] (row stride 33 halves).
    {
        const int ch   = tid >> 3;          // 0..31
        const int part = (tid & 7) << 3;    // 0..56
        const float* __restrict__ src = gp.g[b] + (size_t)ch * (size_t)T + tile0 + part;
        const f32x4 a0 = __builtin_nontemporal_load((const f32x4*)src);
        const f32x4 a1 = __builtin_nontemporal_load((const f32x4*)(src + 4));
#pragma unroll
        for (int k = 0; k < 4; ++k)
            lds[(part + k) * 33 + ch] = __half_as_ushort(__float2half_rn(a0[k]));
#pragma unroll
        for (int k = 0; k < 4; ++k)
            lds[(part + 4 + k) * 33 + ch] = __half_as_ushort(__float2half_rn(a1[k]));
    }
    __syncthreads();

    // stage-out: thread t: tex = t>>2, q = (t&3)*8 -> pack 8 halves, write
    // copy A at texel g, copy B at g-1 (x>=1), edge duplicate B[g] at x==R-1.
    {
        const int tex = tid >> 2;           // 0..63
        const int q   = (tid & 3) << 3;     // 0,8,16,24
        const unsigned short* row = &lds[tex * 33 + q];
        u32x4 v;
#pragma unroll
        for (int k = 0; k < 4; ++k) {
            const unsigned lo = row[2 * k];
            const unsigned hi = row[2 * k + 1];
            v[k] = lo | (hi << 16);
        }
        const int g = tile0 + tex;
        const int x = g & (R - 1);          // R is a power of two

        __half* A = t + go.off[b];
        __half* B = t + TOTAL_HALVES + go.off[b];

        *(u32x4*)(A + (size_t)g * 32 + q) = v;
        if (x >= 1)     *(u32x4*)(B + (size_t)(g - 1) * 32 + q) = v;
        if (x == R - 1) *(u32x4*)(B + (size_t)g       * 32 + q) = v;
    }
}

// ---------------- Phase 2: gather (dual fp16 transposed grids) ------------
__device__ __forceinline__ void h8_to_f(const uint4 u, float f[8])
{
    const __half2* h = (const __half2*)&u;
#pragma unroll
    for (int i = 0; i < 4; ++i) {
        const float2 t = __half22float2(h[i]);
        f[2 * i + 0] = t.x;
        f[2 * i + 1] = t.y;
    }
}

__global__ __launch_bounds__(256) void triplane_sample_h_kernel(
    const float* __restrict__ pts,
    const __half* __restrict__ tg,
    float* __restrict__ out,
    int n_pts)
{
    const int tid = blockIdx.x * 256 + threadIdx.x;
    const int total = n_pts * 36;           // 9 grids * 4 channel-groups
    if (tid >= total) return;

    const int n  = tid / 36;
    const int r  = tid - n * 36;            // 0..35
    const int b  = r >> 2;                  // grid index 0..8
    const int ch = (r & 3) << 3;            // channel start: 0,8,16,24
    const int l  = (b >= 6) ? 2 : (b >= 3 ? 1 : 0);
    const int p  = b - l * 3;               // plane 0,1,2

    const float vx = pts[n * 3 + 0];
    const float vy = pts[n * 3 + 1];
    const float vz = pts[n * 3 + 2];

    // Exactly the reference arithmetic: (v - BOUNDS) * (2/(-2*BOUNDS)) - 1
    const float scale = 2.0f / (-2.0f * 1.6f);   // -0.625
    const float px = (vx - 1.6f) * scale - 1.0f;
    const float py = (vy - 1.6f) * scale - 1.0f;
    const float pz = (vz - 1.6f) * scale - 1.0f;

    // plane 0: (y,z)  plane 1: (x,z)  plane 2: (x,y)
    const float cx = (p == 0) ? py : px;
    const float cy = (p == 2) ? py : pz;

    const int   R   = 128 << l;
    const float Rm1 = (float)(R - 1);

    float x = (cx + 1.0f) * 0.5f * Rm1;
    float y = (cy + 1.0f) * 0.5f * Rm1;
    x = fminf(fmaxf(x, 0.0f), Rm1);
    y = fminf(fmaxf(y, 0.0f), Rm1);

    const float x0f = floorf(x);
    const float y0f = floorf(y);
    const float wx  = x - x0f;
    const float wy  = y - y0f;
    const int x0 = (int)x0f;
    const int y0 = (int)y0f;
    const int y1 = min(y0 + 1, R - 1);

    // Parity-aligned pair read: copy A when x0 even, x-shifted copy B when
    // x0 odd. Either way v00 = block xb, v01 = block xb+1 (same 128-B line),
    // with the x1 = min(x0+1, R-1) clamp baked into copy B's edge column.
    const int par = x0 & 1;
    const int xb  = x0 - par;               // even

    // off(b) = base(l) + p * (524288 << 2l)   [half elements]
    const size_t lbase = (l == 0) ? 0ull : ((l == 1) ? 1572864ull : 7864320ull);
    const size_t off_b = lbase + ((size_t)p << (19 + 2 * l));

    const __half* gbase = tg + (par ? TOTAL_HALVES : 0ull) + off_b + ch;
    const size_t r0 = ((size_t)(y0 * R + xb)) * 32;
    const size_t r1 = ((size_t)(y1 * R + xb)) * 32;

    const uint4 u00 = *(const uint4*)(gbase + r0);
    const uint4 u01 = *(const uint4*)(gbase + r0 + 32);
    const uint4 u10 = *(const uint4*)(gbase + r1);
    const uint4 u11 = *(const uint4*)(gbase + r1 + 32);

    float f00[8], f01[8], f10[8], f11[8];
    h8_to_f(u00, f00);
    h8_to_f(u01, f01);
    h8_to_f(u10, f10);
    h8_to_f(u11, f11);

    const float omwx = 1.0f - wx;
    const float omwy = 1.0f - wy;

    float res[8];
#pragma unroll
    for (int k = 0; k < 8; ++k) {
        res[k] = (f00[k] * omwx + f01[k] * wx) * omwy
               + (f10[k] * omwx + f11[k] * wx) * wy;
    }

    // Nontemporal: the 346 MB output stream must not evict the grids from L3.
    float* op = out + (size_t)n * 288 + b * 32 + ch;
    const f32x4 r0v = {res[0], res[1], res[2], res[3]};
    const f32x4 r1v = {res[4], res[5], res[6], res[7]};
    __builtin_nontemporal_store(r0v, (f32x4*)op);
    __builtin_nontemporal_store(r1v, (f32x4*)(op + 4));
}

// ---------------- Fallback: direct gather on channel-major fp32 grids -----
__global__ __launch_bounds__(256) void triplane_sample_kernel(
    const float* __restrict__ pts,
    GridPtrs gp,
    float* __restrict__ out,
    int n_pts)
{
    const int tid = blockIdx.x * 256 + threadIdx.x;
    const int total = n_pts * 72;
    if (tid >= total) return;

    const int n  = tid / 72;
    const int c4 = tid - n * 72;
    const int b  = c4 >> 3;
    const int ch = (c4 & 7) << 2;
    const int l  = (b >= 6) ? 2 : (b >= 3 ? 1 : 0);
    const int p  = b - l * 3;

    const float vx = pts[n * 3 + 0];
    const float vy = pts[n * 3 + 1];
    const float vz = pts[n * 3 + 2];

    const float scale = 2.0f / (-2.0f * 1.6f);
    const float px = (vx - 1.6f) * scale - 1.0f;
    const float py = (vy - 1.6f) * scale - 1.0f;
    const float pz = (vz - 1.6f) * scale - 1.0f;

    const float cx = (p == 0) ? py : px;
    const float cy = (p == 2) ? py : pz;

    const int   R   = 128 << l;
    const float Rm1 = (float)(R - 1);

    float x = (cx + 1.0f) * 0.5f * Rm1;
    float y = (cy + 1.0f) * 0.5f * Rm1;
    x = fminf(fmaxf(x, 0.0f), Rm1);
    y = fminf(fmaxf(y, 0.0f), Rm1);

    const float x0f = floorf(x);
    const float y0f = floorf(y);
    const float wx  = x - x0f;
    const float wy  = y - y0f;
    const int x0 = (int)x0f;
    const int y0 = (int)y0f;
    const int x1 = min(x0 + 1, R - 1);
    const int y1 = min(y0 + 1, R - 1);

    const size_t RR   = (size_t)R * (size_t)R;
    const float* base = gp.g[b] + (size_t)ch * RR;

    const int i00 = y0 * R + x0;
    const int i01 = y0 * R + x1;
    const int i10 = y1 * R + x0;
    const int i11 = y1 * R + x1;

    const float omwx = 1.0f - wx;
    const float omwy = 1.0f - wy;

    float rr[4];
#pragma unroll
    for (int k = 0; k < 4; ++k) {
        const float* gk = base + (size_t)k * RR;
        rr[k] = (gk[i00] * omwx + gk[i01] * wx) * omwy
              + (gk[i10] * omwx + gk[i11] * wx) * wy;
    }
    ((float4*)out)[tid] = make_float4(rr[0], rr[1], rr[2], rr[3]);
}

extern "C" void kernel_launch(void* const* d_in, const int* in_sizes, int n_in,
                              void* d_out, int out_size, void* d_ws, size_t ws_size,
                              hipStream_t stream)
{
    const float* pts = (const float*)d_in[0];
    GridPtrs gp;
    for (int i = 0; i < 9; ++i) gp.g[i] = (const float*)d_in[1 + i];
    float* out = (float*)d_out;

    const int n_pts = in_sizes[0] / 3;       // 300000
    const int block = 256;

    // Copy-A half-element offsets; copy B lives at +TOTAL_HALVES.
    GridOffs go;
    size_t off = 0;
    for (int b = 0; b < 9; ++b) {
        go.off[b] = off;
        const int R = 128 << (b / 3);
        off += (size_t)32 * R * R;
    }
    const size_t needed_bytes = 2 * off * sizeof(__half);   // ~132 MB (A + B)

    if (ws_size >= needed_bytes) {
        __half* tg = (__half*)d_ws;
        // Phase 1: LDS-tiled transpose+convert, dual-copy write.
        dim3 tgrid(4096, 9, 1);
        transpose_grids_h_kernel<<<tgrid, block, 0, stream>>>(gp, go, tg);
        // Phase 2: gather. 4 threads/(point,grid), 8 channels each.
        const int total = n_pts * 36;
        const int grid  = (total + block - 1) / block;
        triplane_sample_h_kernel<<<grid, block, 0, stream>>>(pts, tg, out, n_pts);
    } else {
        const int total = n_pts * 72;
        const int grid  = (total + block - 1) / block;
        triplane_sample_kernel<<<grid, block, 0, stream>>>(pts, gp, out, n_pts);
    }
}